// Round 7
// baseline (432.356 us; speedup 1.0000x reference)
//
#include <hip/hip_runtime.h>

typedef _Float16 f16_t;
typedef f16_t f16x2 __attribute__((ext_vector_type(2)));
typedef f16_t f16x4 __attribute__((ext_vector_type(4)));
typedef f16_t f16x8 __attribute__((ext_vector_type(8)));
typedef float f32x4 __attribute__((ext_vector_type(4)));
typedef float f32x16 __attribute__((ext_vector_type(16)));

#define MFMA16H(a, b, c) __builtin_amdgcn_mfma_f32_16x16x32_f16(a, b, c, 0, 0, 0)
#define MFMA32H(a, b, c) __builtin_amdgcn_mfma_f32_32x32x16_f16(a, b, c, 0, 0, 0)

__device__ __forceinline__ float leaky01(float v) { return v >= 0.f ? v : 0.01f * v; }

// accumulate one f16x4 row fragment into 4 f32 sums via v_dot2_f32_f16
__device__ __forceinline__ void acc_f16x4(float& s0, float& s1, float& s2, float& s3,
                                          f16x4 v)
{
#if __has_builtin(__builtin_amdgcn_fdot2)
    const f16x2 K10 = (f16x2){(f16_t)1.0f, (f16_t)0.0f};
    const f16x2 K01 = (f16x2){(f16_t)0.0f, (f16_t)1.0f};
    f16x2 lo = (f16x2){v.x, v.y};
    f16x2 hi = (f16x2){v.z, v.w};
    s0 = __builtin_amdgcn_fdot2(lo, K10, s0, false);
    s1 = __builtin_amdgcn_fdot2(lo, K01, s1, false);
    s2 = __builtin_amdgcn_fdot2(hi, K10, s2, false);
    s3 = __builtin_amdgcn_fdot2(hi, K01, s3, false);
#else
    s0 += (float)v.x; s1 += (float)v.y; s2 += (float)v.z; s3 += (float)v.w;
#endif
}

// packed-weight offsets (f16 elements)
#define OFF_IW1 0         // 256x128
#define OFF_IW2 32768     // 128x128
#define OFF_IW3 49152     // 128x256
#define OFF_AW1 81920     // 256x128
#define OFF_AW2 114688    // 128x128
#define OFF_AW3 131072    // 128x256
#define OFF_PW1 163840    // 256x256
#define OFF_PW2 229376    // 256x256
#define OFF_M3  294912    // 128x128
#define WP_TOTAL 311296

// ---------------------------------------------------------------------------
// Narrow (128-col) GEMM, 32 rows: 8 waves x 16 cols, 2 row-tiles of 16.
// ---------------------------------------------------------------------------
template<int KD, int NC>
__device__ __forceinline__ void gemm16(
    const f16_t* __restrict__ a, int sa, const f16_t* __restrict__ B,
    int cb, int qd, int ln, f32x4 (&acc)[2])
{
    acc[0] = (f32x4){0.f, 0.f, 0.f, 0.f};
    acc[1] = acc[0];
#pragma unroll
    for (int k0 = 0; k0 < KD; k0 += 32) {
        int ka = k0 + qd * 8;
        f16x8 b = *(const f16x8*)(B + ((size_t)((k0 >> 5) * 4 + qd) * NC + cb + ln) * 8);
        f16x8 a0 = *(const f16x8*)&a[ln * sa + ka];
        f16x8 a1 = *(const f16x8*)&a[(16 + ln) * sa + ka];
        acc[0] = MFMA16H(a0, b, acc[0]);
        acc[1] = MFMA16H(a1, b, acc[1]);
    }
}

// ---------------------------------------------------------------------------
// Wide GEMM, 32 rows: per wave 32 cols x one 32-row subtile.
// ---------------------------------------------------------------------------
template<int KD, int NC>
__device__ __forceinline__ void gemm32(
    const f16_t* __restrict__ a, int sa, const f16_t* __restrict__ B,
    int cb, int l31, int kh, f32x16 &o)
{
    f32x16 c;
#pragma unroll
    for (int i = 0; i < 16; ++i) c[i] = 0.f;
    const int ar = l31 * sa + kh * 8;
    const int bcol = cb + l31;
#pragma unroll
    for (int kc = 0; kc < KD; kc += 32) {
        f16x8 b0 = *(const f16x8*)(B + ((size_t)((kc >> 3) + kh) * NC + bcol) * 8);
        f16x8 b1 = *(const f16x8*)(B + ((size_t)((kc >> 3) + 2 + kh) * NC + bcol) * 8);
        f16x8 a0 = *(const f16x8*)&a[ar + kc];
        f16x8 a1 = *(const f16x8*)&a[ar + kc + 16];
        c = MFMA32H(a0, b0, c);
        c = MFMA32H(a1, b1, c);
    }
    o = c;
}

// narrow epilogue -> f16 LDS. act: 0 none, 1 leaky, 2 relu
template<int ACT>
__device__ __forceinline__ void epi16(
    f32x4 (&acc)[2], const float* __restrict__ bias,
    int cb, int qd, int ln, f16_t* d, int stride)
{
    int col = cb + ln;
    float bb = bias[col];
#pragma unroll
    for (int rt = 0; rt < 2; ++rt)
#pragma unroll
        for (int r = 0; r < 4; ++r) {
            float v = acc[rt][r] + bb;
            if (ACT == 1) v = leaky01(v);
            else if (ACT == 2) v = fmaxf(v, 0.f);
            d[(rt * 16 + qd * 4 + r) * stride + col] = (f16_t)v;
        }
}

// wide epilogue -> f16 LDS. C/D layout: col=lane&31, row=(r&3)+8*(r>>2)+4*kh.
template<int ACT>
__device__ __forceinline__ void epi32(
    const f32x16 &a0, const float* __restrict__ bias,
    int cb, int l31, int kh, f16_t* d, int stride)
{
    int col = cb + l31;
    float bb = bias[col];
#pragma unroll
    for (int r = 0; r < 16; ++r) {
        float v = a0[r] + bb;
        if (ACT == 1) v = leaky01(v);
        else if (ACT == 2) v = fmaxf(v, 0.f);
        int row = (r & 3) + 8 * (r >> 2) + 4 * kh;
        d[row * stride + col] = (f16_t)v;
    }
}

// ---------------------------------------------------------------------------
// prep_kernel: ONE launch for {weight pack, M3 = iW3@aW1, c3 = ib3@aW1,
// CSR edge count} — all mutually independent block ranges.
//   bid <  1024      : pack plane m = bid>>7, chunk bx = bid&127
//   bid in [1024,1056): M3 (32 blocks x 512 = 16384 elems)
//   bid == 1056      : c3
//   bid >= 1057      : edge count, e = (bid-1057)*512 + tid
// ---------------------------------------------------------------------------
__global__ __launch_bounds__(512) void prep_kernel(
    const float* s0, const float* s1, const float* s2, const float* s3,
    const float* s4, const float* s5, const float* s6, const float* s7,
    const float* __restrict__ ib3, f16_t* dst, float* __restrict__ c3f,
    const int* __restrict__ dstE, int* __restrict__ cnt, int E)
{
    const int tid = threadIdx.x;
    const int bid = blockIdx.x;

    if (bid < 1024) {                     // weight pack
        const float* srcs[8] = {s0, s1, s2, s3, s4, s5, s6, s7};
        const int lgN[8] = {7, 7, 8, 7, 7, 8, 8, 8};
        const int sz[8]  = {32768, 16384, 32768, 32768, 16384, 32768, 65536, 65536};
        const int off[8] = {OFF_IW1, OFF_IW2, OFF_IW3, OFF_AW1, OFF_AW2, OFF_AW3,
                            OFF_PW1, OFF_PW2};
        int m = bid >> 7;
        int idx = (bid & 127) * 512 + tid;
        if (idx >= sz[m]) return;
        int lg = lgN[m];
        int Nc = 1 << lg;
        int k = idx >> lg;
        int n = idx & (Nc - 1);
        int p = ((k >> 3) * Nc + n) * 8 + (k & 7);
        dst[off[m] + p] = (f16_t)srcs[m][idx];
    } else if (bid < 1056) {              // M3 = iW3 @ aW1
        int idx = (bid - 1024) * 512 + tid;    // < 16384
        int k = idx >> 7, j = idx & 127;
        float s = 0.f;
        for (int t = 0; t < 256; ++t) s += s2[k * 256 + t] * s3[t * 128 + j];
        int p = ((k >> 3) * 128 + j) * 8 + (k & 7);
        dst[OFF_M3 + p] = (f16_t)s;
    } else if (bid == 1056) {             // c3 = ib3 @ aW1
        int j = tid;
        if (j < 128) {
            float s = 0.f;
            for (int t = 0; t < 256; ++t) s += ib3[t] * s3[t * 128 + j];
            c3f[j] = s;
        }
    } else {                              // CSR edge count
        int e = (bid - 1057) * 512 + tid;
        if (e < E) atomicAdd(&cnt[dstE[e]], 1);
    }
}

// ---------------------------------------------------------------------------
// scan_all: entire exclusive scan of cnt in ONE 512-thread block.
// Thread t serial-sums its contiguous chunk, block-scans the 512 partials,
// then walks its chunk writing offs & cursor.
// ---------------------------------------------------------------------------
__global__ __launch_bounds__(512) void scan_all(
    const int* __restrict__ cnt, int* __restrict__ offs,
    int* __restrict__ cursor, int Nn)
{
    __shared__ int s[512];
    const int tid = threadIdx.x;
    const int per = (Nn + 511) / 512;
    int lo = tid * per;
    int hi = lo + per; if (hi > Nn) hi = Nn;
    int sum = 0;
    for (int i = lo; i < hi; ++i) sum += cnt[i];
    s[tid] = sum;
    __syncthreads();
    for (int off = 1; off < 512; off <<= 1) {
        int u = (tid >= off) ? s[tid - off] : 0;
        __syncthreads();
        s[tid] += u;
        __syncthreads();
    }
    int run = s[tid] - sum;               // exclusive prefix of this chunk
    for (int i = lo; i < hi; ++i) {
        offs[i] = run;
        cursor[i] = run;
        run += cnt[i];
    }
}

// ---------------------------------------------------------------------------
// fillA: kernelA blocks (bid < tiles) concurrent with CSR fill blocks.
// kernelA: 512 thr / 32 rows. Dual wide: waves 0-3 z = h@aW1, waves 4-7
// y1 = leaky(h@iW1+ib1). Then y2 = leaky(y1@iW2+ib2); zinv = y2@M3 + c3.
// z staged into dead upper half of X, zinv into dead Y; coalesced store.
// fill: ridx[atomic cursor[dst]] = src*2 + r.
// ---------------------------------------------------------------------------
__global__ __launch_bounds__(512, 8) void fillA(
    const float* __restrict__ h, f16_t* __restrict__ zbuf,
    const f16_t* __restrict__ wp, const float* __restrict__ ib1,
    const float* __restrict__ ib2, const float* __restrict__ c3f, int M,
    int tiles, const int* __restrict__ dstE, const int* __restrict__ srcE,
    const int* __restrict__ rE, int* __restrict__ cursor,
    int* __restrict__ ridx, int E)
{
    __shared__ f16_t X[32][264];
    __shared__ f16_t Y[32][136];

    const int tid = threadIdx.x;

    if ((int)blockIdx.x >= tiles) {       // CSR fill blocks
        int e = (blockIdx.x - tiles) * 512 + tid;
        if (e < E) {
            int p = atomicAdd(&cursor[dstE[e]], 1);
            ridx[p] = srcE[e] * 2 + rE[e];
        }
        return;
    }

    const int row0 = blockIdx.x * 32;
    const int lane = tid & 63;
    const int wv = tid >> 6;          // 0..7
    const int qd = lane >> 4;
    const int ln = lane & 15;
    const int cb = wv * 16;
    const int l31 = lane & 31;
    const int kh = lane >> 5;

    // stage h (32 x 256 fp32) -> f16
    {
        const float4* src4 = (const float4*)(h + (size_t)row0 * 256);
#pragma unroll
        for (int i = 0; i < 4; ++i) {
            int q = i * 512 + tid;
            int row = q >> 6;
            int kc = (q & 63) * 4;
            float4 v = make_float4(0.f, 0.f, 0.f, 0.f);
            if (row0 + row < M) v = src4[q];
            *(f16x4*)&X[row][kc] = (f16x4){(f16_t)v.x, (f16_t)v.y, (f16_t)v.z, (f16_t)v.w};
        }
    }
    __syncthreads();

    // dual wide: waves 0-3 -> z (aW1), waves 4-7 -> y1 (iW1); 32 cols/wave
    {
        const bool isz = wv < 4;
        const int cb32 = (wv & 3) * 32;
        const f16_t* Bw = wp + (isz ? OFF_AW1 : OFF_IW1);
        f32x16 z;
        gemm32<256, 128>(&X[0][0], 264, Bw, cb32, l31, kh, z);
        __syncthreads();   // all waves done reading h
        int col = cb32 + l31;
        if (isz) {
            // z -> X[:, 128+col] (staged for the coalesced store)
#pragma unroll
            for (int r = 0; r < 16; ++r) {
                int lrow = (r & 3) + 8 * (r >> 2) + 4 * kh;
                X[lrow][128 + col] = (f16_t)z[r];
            }
        } else {
            float bb = ib1[col];
#pragma unroll
            for (int r = 0; r < 16; ++r) {
                int lrow = (r & 3) + 8 * (r >> 2) + 4 * kh;
                Y[lrow][col] = (f16_t)leaky01(z[r] + bb);
            }
        }
    }
    __syncthreads();

    f32x4 a4[2];

    // y2 = leaky(y1@iW2 + ib2) -> X cols 0..127 (h dead; z at 128..255)
    gemm16<128, 128>(&Y[0][0], 136, wp + OFF_IW2, cb, qd, ln, a4);
    epi16<1>(a4, ib2, cb, qd, ln, &X[0][0], 264);
    __syncthreads();

    // zinv = y2 @ M3 + c3 -> Y (y1 dead)
    gemm16<128, 128>(&X[0][0], 264, wp + OFF_M3, cb, qd, ln, a4);
    {
        int col = cb + ln;
        float bb = c3f[col];
#pragma unroll
        for (int rt = 0; rt < 2; ++rt)
#pragma unroll
            for (int r = 0; r < 4; ++r)
                Y[rt * 16 + qd * 4 + r][col] = (f16_t)(a4[rt][r] + bb);
    }
    __syncthreads();

    // coalesced store: per node 512B contiguous = [z | zinv]
#pragma unroll
    for (int i = 0; i < 2; ++i) {
        int q = i * 512 + tid;
        int node = q >> 5;
        int seg = q & 31;
        int row = row0 + node;
        if (row < M) {
            f16x8 v = (seg < 16) ? *(const f16x8*)&X[node][128 + seg * 8]
                                 : *(const f16x8*)&Y[node][(seg - 16) * 8];
            *(f16x8*)&zbuf[(size_t)row * 256 + seg * 8] = v;
        }
    }
}

// ---------------------------------------------------------------------------
// kernelB: 512 thr / 32 rows. Phase 0 = mean gather (half-wave per node,
// 2 passes). Buffer ping-pong A/B2/C trims barriers 12 -> 8.
// ---------------------------------------------------------------------------
__global__ __launch_bounds__(512, 8) void kernelB(
    const f16_t* __restrict__ zbuf, const int* __restrict__ ridx,
    const int* __restrict__ offs, const int* __restrict__ cnt,
    const float* __restrict__ ab1, const int* __restrict__ invf,
    float* __restrict__ out, const f16_t* __restrict__ wp,
    const float* __restrict__ ab2, const float* __restrict__ ab3,
    const float* __restrict__ ib1, const float* __restrict__ ib2,
    const float* __restrict__ ib3, const float* __restrict__ pb1,
    const float* __restrict__ pb2, int M)
{
    __shared__ f16_t C[32][264];
    __shared__ f16_t A[32][136];
    __shared__ f16_t B2[32][136];
    __shared__ int sflag[32];

    const int tid = threadIdx.x;
    const int row0 = blockIdx.x * 32;
    const int lane = tid & 63;
    const int wv = tid >> 6;
    const int qd = lane >> 4;
    const int ln = lane & 15;
    const int cb2 = wv * 16;
    const int l31 = lane & 31;
    const int kh = lane >> 5;
    const int cb32 = wv * 32;

    // ---- phase 0: mean gather, half-wave (32 lanes x f16x4 = 256B row) per node
    const int hw = tid >> 5;          // half-wave 0..15
    const int hl = tid & 31;          // lane in half
    const int hbase = lane & 32;      // shfl base within wave
    const f16x4* zp4 = (const f16x4*)zbuf;   // row = 32 f16x4

#pragma unroll
    for (int pass = 0; pass < 2; ++pass) {
        int nl = pass * 16 + hw;
        int row = row0 + nl;
        float s0 = 0.f, s1 = 0.f, s2 = 0.f, s3 = 0.f;
        int c = 0;
        if (row < M) {
            int beg = offs[row];
            c = cnt[row];
            for (int base = 0; base < c; base += 32) {
                int rem = c - base; if (rem > 32) rem = 32;
                int myr = (hl < rem) ? ridx[beg + base + hl] : 0;
                int j = 0;
                for (; j + 16 <= rem; j += 16) {
                    f16x4 v[16];
#pragma unroll
                    for (int i = 0; i < 16; ++i) {
                        int rr = __shfl(myr, hbase + j + i);
                        v[i] = zp4[(size_t)rr * 32 + hl];
                    }
#pragma unroll
                    for (int i = 0; i < 16; ++i)
                        acc_f16x4(s0, s1, s2, s3, v[i]);
                }
                for (; j + 8 <= rem; j += 8) {
                    f16x4 v[8];
#pragma unroll
                    for (int i = 0; i < 8; ++i) {
                        int rr = __shfl(myr, hbase + j + i);
                        v[i] = zp4[(size_t)rr * 32 + hl];
                    }
#pragma unroll
                    for (int i = 0; i < 8; ++i)
                        acc_f16x4(s0, s1, s2, s3, v[i]);
                }
                for (; j < rem; ++j) {
                    int rr = __shfl(myr, hbase + j);
                    f16x4 vv = zp4[(size_t)rr * 32 + hl];
                    acc_f16x4(s0, s1, s2, s3, vv);
                }
            }
        }
        float invc = 1.0f / fmaxf((float)c, 1.0f);
        float4 bv = *(const float4*)&ab1[hl * 4];
        float m0 = leaky01(s0 * invc + bv.x);
        float m1 = leaky01(s1 * invc + bv.y);
        float m2 = leaky01(s2 * invc + bv.z);
        float m3 = leaky01(s3 * invc + bv.w);
        *(f16x4*)&A[nl][hl * 4] = (f16x4){(f16_t)m0, (f16_t)m1, (f16_t)m2, (f16_t)m3};
    }
    if (tid < 32) {
        int rr = row0 + tid;
        sflag[tid] = (rr < M) ? invf[rr] : 0;
    }
    __syncthreads();                                   // S1: A, sflag ready

    f32x4 a4[2];
    f32x16 c32;

    // L2a: u = leaky(y@aW2 + ab2): A -> B2
    gemm16<128, 128>(&A[0][0], 136, wp + OFF_AW2, cb2, qd, ln, a4);
    epi16<1>(a4, ab2, cb2, qd, ln, &B2[0][0], 136);
    __syncthreads();                                   // S2: B2 ready

    // L3a: res = u@aW3 + ab3: B2 -> C
    gemm32<128, 256>(&B2[0][0], 136, wp + OFF_AW3, cb32, l31, kh, c32);
    epi32<0>(c32, ab3, cb32, l31, kh, &C[0][0], 264);
    __syncthreads();                                   // S3: C ready

    // inv layer1: t1 = leaky(res@iW1 + ib1): C -> A  (A dead since S2)
    gemm16<256, 128>(&C[0][0], 264, wp + OFF_IW1, cb2, qd, ln, a4);
    epi16<1>(a4, ib1, cb2, qd, ln, &A[0][0], 136);
    __syncthreads();                                   // S4: A ready

    // inv layer2: t2 = leaky(t1@iW2 + ib2): A -> B2  (B2 dead since S3)
    gemm16<128, 128>(&A[0][0], 136, wp + OFF_IW2, cb2, qd, ln, a4);
    epi16<1>(a4, ib2, cb2, qd, ln, &B2[0][0], 136);
    __syncthreads();                                   // S5: B2 ready

    // inv layer3: overwrite C rows where flag set: B2 -> C-masked
    gemm32<128, 256>(&B2[0][0], 136, wp + OFF_IW3, cb32, l31, kh, c32);
    {
        int col = cb32 + l31;
        float bb = ib3[col];
#pragma unroll
        for (int r = 0; r < 16; ++r) {
            int lrow = (r & 3) + 8 * (r >> 2) + 4 * kh;
            if (sflag[lrow] == 1) C[lrow][col] = (f16_t)(c32[r] + bb);
        }
    }
    __syncthreads();                                   // S6: C (selected) ready

    // proj1: p1 = relu(sel@pW1 + pb1): C -> C (in place)
    gemm32<256, 256>(&C[0][0], 264, wp + OFF_PW1, cb32, l31, kh, c32);
    __syncthreads();                                   // S7: all reads of C done
    epi32<2>(c32, pb1, cb32, l31, kh, &C[0][0], 264);
    __syncthreads();                                   // S8: C ready

    // proj2 -> out
    gemm32<256, 256>(&C[0][0], 264, wp + OFF_PW2, cb32, l31, kh, c32);
    {
        int col = cb32 + l31;
        float bb = pb2[col];
#pragma unroll
        for (int r = 0; r < 16; ++r) {
            int lrow = (r & 3) + 8 * (r >> 2) + 4 * kh;
            int row = row0 + lrow;
            if (row < M) out[(size_t)row * 256 + col] = c32[r] + bb;
        }
    }
}

extern "C" void kernel_launch(void* const* d_in, const int* in_sizes, int n_in,
                              void* d_out, int out_size, void* d_ws, size_t ws_size,
                              hipStream_t stream)
{
    const float* h   = (const float*)d_in[0];
    const int* src   = (const int*)d_in[1];
    const int* dst   = (const int*)d_in[2];
    const int* r     = (const int*)d_in[3];
    const int* inv   = (const int*)d_in[4];
    const float* iW1 = (const float*)d_in[5];
    const float* ib1 = (const float*)d_in[6];
    const float* iW2 = (const float*)d_in[7];
    const float* ib2 = (const float*)d_in[8];
    const float* iW3 = (const float*)d_in[9];
    const float* ib3 = (const float*)d_in[10];
    const float* aW1 = (const float*)d_in[11];
    const float* ab1 = (const float*)d_in[12];
    const float* aW2 = (const float*)d_in[13];
    const float* ab2 = (const float*)d_in[14];
    const float* aW3 = (const float*)d_in[15];
    const float* ab3 = (const float*)d_in[16];
    const float* pW1 = (const float*)d_in[17];
    const float* pb1 = (const float*)d_in[18];
    const float* pW2 = (const float*)d_in[19];
    const float* pb2 = (const float*)d_in[20];

    const int N = in_sizes[0] / 256;
    const int E = in_sizes[1];
    float* out = (float*)d_out;

    // workspace carve-up
    f16_t* zbuf = (f16_t*)d_ws;                        // 2N*128 f16 (z|zinv per node)
    int* cnt    = (int*)(zbuf + (size_t)2 * N * 128);  // N
    int* offs   = cnt + N;                             // N
    int* cursor = offs + N;                            // N
    int* bsum   = cursor + N;                          // 256 (spare)
    int* ridx   = bsum + 256;                          // E
    f16_t* wp   = (f16_t*)(ridx + E);                  // WP_TOTAL packed f16
    float* c3f  = (float*)(wp + WP_TOTAL);             // 128

    (void)hipMemsetAsync(cnt, 0, (size_t)N * sizeof(int), stream);

    const int tiles = (N + 31) / 32;
    const int EB = (E + 511) / 512;

    // 1) pack + M3/c3 + edge count (one launch; independent block ranges)
    prep_kernel<<<1057 + EB, 512, 0, stream>>>(iW1, iW2, iW3, aW1, aW2, aW3,
                                               pW1, pW2, ib3, wp, c3f,
                                               dst, cnt, E);

    // 2) whole CSR scan in one block
    scan_all<<<1, 512, 0, stream>>>(cnt, offs, cursor, N);

    // 3) kernelA blocks + CSR fill blocks, concurrent
    fillA<<<tiles + EB, 512, 0, stream>>>(h, zbuf, wp, ib1, ib2, c3f, N,
                                          tiles, dst, src, r, cursor, ridx, E);

    // 4) fused: mean gather + L2a,L3a + cond inv-MLP + proj1,proj2
    kernelB<<<tiles, 512, 0, stream>>>(zbuf, ridx, offs, cnt, ab1, inv, out, wp,
                                       ab2, ab3, ib1, ib2, ib3, pb1, pb2, N);
}

// Round 8
// 322.951 us; speedup vs baseline: 1.3388x; 1.3388x over previous
//
#include <hip/hip_runtime.h>

typedef _Float16 f16_t;
typedef f16_t f16x2 __attribute__((ext_vector_type(2)));
typedef f16_t f16x4 __attribute__((ext_vector_type(4)));
typedef f16_t f16x8 __attribute__((ext_vector_type(8)));
typedef float f32x4 __attribute__((ext_vector_type(4)));
typedef float f32x16 __attribute__((ext_vector_type(16)));

#define MFMA16H(a, b, c) __builtin_amdgcn_mfma_f32_16x16x32_f16(a, b, c, 0, 0, 0)
#define MFMA32H(a, b, c) __builtin_amdgcn_mfma_f32_32x32x16_f16(a, b, c, 0, 0, 0)

__device__ __forceinline__ float leaky01(float v) { return v >= 0.f ? v : 0.01f * v; }

// accumulate one f16x4 row fragment into 4 f32 sums via v_dot2_f32_f16
__device__ __forceinline__ void acc_f16x4(float& s0, float& s1, float& s2, float& s3,
                                          f16x4 v)
{
#if __has_builtin(__builtin_amdgcn_fdot2)
    const f16x2 K10 = (f16x2){(f16_t)1.0f, (f16_t)0.0f};
    const f16x2 K01 = (f16x2){(f16_t)0.0f, (f16_t)1.0f};
    f16x2 lo = (f16x2){v.x, v.y};
    f16x2 hi = (f16x2){v.z, v.w};
    s0 = __builtin_amdgcn_fdot2(lo, K10, s0, false);
    s1 = __builtin_amdgcn_fdot2(lo, K01, s1, false);
    s2 = __builtin_amdgcn_fdot2(hi, K10, s2, false);
    s3 = __builtin_amdgcn_fdot2(hi, K01, s3, false);
#else
    s0 += (float)v.x; s1 += (float)v.y; s2 += (float)v.z; s3 += (float)v.w;
#endif
}

// packed-weight offsets (f16 elements)
#define OFF_IW1 0         // 256x128
#define OFF_IW2 32768     // 128x128
#define OFF_IW3 49152     // 128x256
#define OFF_AW1 81920     // 256x128
#define OFF_AW2 114688    // 128x128
#define OFF_AW3 131072    // 128x256
#define OFF_PW1 163840    // 256x256
#define OFF_PW2 229376    // 256x256
#define OFF_M3  294912    // 128x128
#define WP_TOTAL 311296

// ---------------------------------------------------------------------------
// Narrow (128-col) GEMM, 32 rows: 8 waves x 16 cols, 2 row-tiles of 16.
// ---------------------------------------------------------------------------
template<int KD, int NC>
__device__ __forceinline__ void gemm16(
    const f16_t* __restrict__ a, int sa, const f16_t* __restrict__ B,
    int cb, int qd, int ln, f32x4 (&acc)[2])
{
    acc[0] = (f32x4){0.f, 0.f, 0.f, 0.f};
    acc[1] = acc[0];
#pragma unroll
    for (int k0 = 0; k0 < KD; k0 += 32) {
        int ka = k0 + qd * 8;
        f16x8 b = *(const f16x8*)(B + ((size_t)((k0 >> 5) * 4 + qd) * NC + cb + ln) * 8);
        f16x8 a0 = *(const f16x8*)&a[ln * sa + ka];
        f16x8 a1 = *(const f16x8*)&a[(16 + ln) * sa + ka];
        acc[0] = MFMA16H(a0, b, acc[0]);
        acc[1] = MFMA16H(a1, b, acc[1]);
    }
}

// ---------------------------------------------------------------------------
// Wide GEMM, 32 rows: per wave 32 cols x one 32-row subtile.
// ---------------------------------------------------------------------------
template<int KD, int NC>
__device__ __forceinline__ void gemm32(
    const f16_t* __restrict__ a, int sa, const f16_t* __restrict__ B,
    int cb, int l31, int kh, f32x16 &o)
{
    f32x16 c;
#pragma unroll
    for (int i = 0; i < 16; ++i) c[i] = 0.f;
    const int ar = l31 * sa + kh * 8;
    const int bcol = cb + l31;
#pragma unroll
    for (int kc = 0; kc < KD; kc += 32) {
        f16x8 b0 = *(const f16x8*)(B + ((size_t)((kc >> 3) + kh) * NC + bcol) * 8);
        f16x8 b1 = *(const f16x8*)(B + ((size_t)((kc >> 3) + 2 + kh) * NC + bcol) * 8);
        f16x8 a0 = *(const f16x8*)&a[ar + kc];
        f16x8 a1 = *(const f16x8*)&a[ar + kc + 16];
        c = MFMA32H(a0, b0, c);
        c = MFMA32H(a1, b1, c);
    }
    o = c;
}

// narrow epilogue -> f16 LDS. act: 0 none, 1 leaky, 2 relu
template<int ACT>
__device__ __forceinline__ void epi16(
    f32x4 (&acc)[2], const float* __restrict__ bias,
    int cb, int qd, int ln, f16_t* d, int stride)
{
    int col = cb + ln;
    float bb = bias[col];
#pragma unroll
    for (int rt = 0; rt < 2; ++rt)
#pragma unroll
        for (int r = 0; r < 4; ++r) {
            float v = acc[rt][r] + bb;
            if (ACT == 1) v = leaky01(v);
            else if (ACT == 2) v = fmaxf(v, 0.f);
            d[(rt * 16 + qd * 4 + r) * stride + col] = (f16_t)v;
        }
}

// wide epilogue -> f16 LDS. C/D layout: col=lane&31, row=(r&3)+8*(r>>2)+4*kh.
template<int ACT>
__device__ __forceinline__ void epi32(
    const f32x16 &a0, const float* __restrict__ bias,
    int cb, int l31, int kh, f16_t* d, int stride)
{
    int col = cb + l31;
    float bb = bias[col];
#pragma unroll
    for (int r = 0; r < 16; ++r) {
        float v = a0[r] + bb;
        if (ACT == 1) v = leaky01(v);
        else if (ACT == 2) v = fmaxf(v, 0.f);
        int row = (r & 3) + 8 * (r >> 2) + 4 * kh;
        d[row * stride + col] = (f16_t)v;
    }
}

// ---------------------------------------------------------------------------
// prep_kernel: ONE launch for {weight pack, M3 = iW3@aW1, c3 = ib3@aW1,
// CSR edge count} — all mutually independent block ranges.
// ---------------------------------------------------------------------------
__global__ __launch_bounds__(512) void prep_kernel(
    const float* s0, const float* s1, const float* s2, const float* s3,
    const float* s4, const float* s5, const float* s6, const float* s7,
    const float* __restrict__ ib3, f16_t* dst, float* __restrict__ c3f,
    const int* __restrict__ dstE, int* __restrict__ cnt, int E)
{
    const int tid = threadIdx.x;
    const int bid = blockIdx.x;

    if (bid < 1024) {                     // weight pack
        const float* srcs[8] = {s0, s1, s2, s3, s4, s5, s6, s7};
        const int lgN[8] = {7, 7, 8, 7, 7, 8, 8, 8};
        const int sz[8]  = {32768, 16384, 32768, 32768, 16384, 32768, 65536, 65536};
        const int off[8] = {OFF_IW1, OFF_IW2, OFF_IW3, OFF_AW1, OFF_AW2, OFF_AW3,
                            OFF_PW1, OFF_PW2};
        int m = bid >> 7;
        int idx = (bid & 127) * 512 + tid;
        if (idx >= sz[m]) return;
        int lg = lgN[m];
        int Nc = 1 << lg;
        int k = idx >> lg;
        int n = idx & (Nc - 1);
        int p = ((k >> 3) * Nc + n) * 8 + (k & 7);
        dst[off[m] + p] = (f16_t)srcs[m][idx];
    } else if (bid < 1056) {              // M3 = iW3 @ aW1
        int idx = (bid - 1024) * 512 + tid;    // < 16384
        int k = idx >> 7, j = idx & 127;
        float s = 0.f;
        for (int t = 0; t < 256; ++t) s += s2[k * 256 + t] * s3[t * 128 + j];
        int p = ((k >> 3) * 128 + j) * 8 + (k & 7);
        dst[OFF_M3 + p] = (f16_t)s;
    } else if (bid == 1056) {             // c3 = ib3 @ aW1
        int j = tid;
        if (j < 128) {
            float s = 0.f;
            for (int t = 0; t < 256; ++t) s += ib3[t] * s3[t * 128 + j];
            c3f[j] = s;
        }
    } else {                              // CSR edge count
        int e = (bid - 1057) * 512 + tid;
        if (e < E) atomicAdd(&cnt[dstE[e]], 1);
    }
}

// ---------------------------------------------------------------------------
// CSR scan: multi-block (proven fast path). scan1 -> scan3b (merged scan2).
// ---------------------------------------------------------------------------
__global__ void scan1(const int* __restrict__ cnt, int* __restrict__ offs,
                      int* __restrict__ bsum, int Nn)
{
    __shared__ int s[256];
    int tid = threadIdx.x;
    int g = blockIdx.x * 256 + tid;
    int v = (g < Nn) ? cnt[g] : 0;
    s[tid] = v;
    __syncthreads();
    for (int off = 1; off < 256; off <<= 1) {
        int u = (tid >= off) ? s[tid - off] : 0;
        __syncthreads();
        s[tid] += u;
        __syncthreads();
    }
    if (g < Nn) offs[g] = s[tid] - v;          // block-exclusive
    if (tid == 255) bsum[blockIdx.x] = s[255];
}

// requires NB <= 256 (true at N=50k: NB=196)
__global__ void scan3b(int* __restrict__ offs, const int* __restrict__ bsum,
                       int* __restrict__ cursor, int Nn, int NB)
{
    __shared__ int s[256];
    int tid = threadIdx.x;
    int bid = blockIdx.x;
    int v = (tid < NB) ? bsum[tid] : 0;
    s[tid] = v;
    __syncthreads();
    for (int off = 1; off < 256; off <<= 1) {
        int u = (tid >= off) ? s[tid - off] : 0;
        __syncthreads();
        s[tid] += u;
        __syncthreads();
    }
    int base = (bid > 0) ? s[bid - 1] : 0;     // sum of bsum[0..bid-1]
    int g = bid * 256 + tid;
    if (g < Nn) {
        int o = offs[g] + base;
        offs[g] = o;
        cursor[g] = o;
    }
}

// fallback path kernels (NB > 256; unused at N=50k)
__global__ void scan2(int* __restrict__ bsum, int NB)
{
    if (threadIdx.x == 0) {
        int run = 0;
        for (int i = 0; i < NB; ++i) { int v = bsum[i]; bsum[i] = run; run += v; }
    }
}

__global__ void scan3(int* __restrict__ offs, const int* __restrict__ bsum,
                      int* __restrict__ cursor, int Nn)
{
    int g = blockIdx.x * 256 + threadIdx.x;
    if (g < Nn) {
        int o = offs[g] + bsum[blockIdx.x];
        offs[g] = o;
        cursor[g] = o;
    }
}

// ---------------------------------------------------------------------------
// fillA: kernelA blocks (bid < tiles) concurrent with CSR fill blocks.
// ---------------------------------------------------------------------------
__global__ __launch_bounds__(512, 8) void fillA(
    const float* __restrict__ h, f16_t* __restrict__ zbuf,
    const f16_t* __restrict__ wp, const float* __restrict__ ib1,
    const float* __restrict__ ib2, const float* __restrict__ c3f, int M,
    int tiles, const int* __restrict__ dstE, const int* __restrict__ srcE,
    const int* __restrict__ rE, int* __restrict__ cursor,
    int* __restrict__ ridx, int E)
{
    __shared__ f16_t X[32][264];
    __shared__ f16_t Y[32][136];

    const int tid = threadIdx.x;

    if ((int)blockIdx.x >= tiles) {       // CSR fill blocks
        int e = (blockIdx.x - tiles) * 512 + tid;
        if (e < E) {
            int p = atomicAdd(&cursor[dstE[e]], 1);
            ridx[p] = srcE[e] * 2 + rE[e];
        }
        return;
    }

    const int row0 = blockIdx.x * 32;
    const int lane = tid & 63;
    const int wv = tid >> 6;          // 0..7
    const int qd = lane >> 4;
    const int ln = lane & 15;
    const int cb = wv * 16;
    const int l31 = lane & 31;
    const int kh = lane >> 5;

    // stage h (32 x 256 fp32) -> f16
    {
        const float4* src4 = (const float4*)(h + (size_t)row0 * 256);
#pragma unroll
        for (int i = 0; i < 4; ++i) {
            int q = i * 512 + tid;
            int row = q >> 6;
            int kc = (q & 63) * 4;
            float4 v = make_float4(0.f, 0.f, 0.f, 0.f);
            if (row0 + row < M) v = src4[q];
            *(f16x4*)&X[row][kc] = (f16x4){(f16_t)v.x, (f16_t)v.y, (f16_t)v.z, (f16_t)v.w};
        }
    }
    __syncthreads();

    // dual wide: waves 0-3 -> z (aW1), waves 4-7 -> y1 (iW1); 32 cols/wave
    {
        const bool isz = wv < 4;
        const int cb32 = (wv & 3) * 32;
        const f16_t* Bw = wp + (isz ? OFF_AW1 : OFF_IW1);
        f32x16 z;
        gemm32<256, 128>(&X[0][0], 264, Bw, cb32, l31, kh, z);
        __syncthreads();   // all waves done reading h
        int col = cb32 + l31;
        if (isz) {
            // z -> X[:, 128+col] (staged for the coalesced store)
#pragma unroll
            for (int r = 0; r < 16; ++r) {
                int lrow = (r & 3) + 8 * (r >> 2) + 4 * kh;
                X[lrow][128 + col] = (f16_t)z[r];
            }
        } else {
            float bb = ib1[col];
#pragma unroll
            for (int r = 0; r < 16; ++r) {
                int lrow = (r & 3) + 8 * (r >> 2) + 4 * kh;
                Y[lrow][col] = (f16_t)leaky01(z[r] + bb);
            }
        }
    }
    __syncthreads();

    f32x4 a4[2];

    // y2 = leaky(y1@iW2 + ib2) -> X cols 0..127 (h dead; z at 128..255)
    gemm16<128, 128>(&Y[0][0], 136, wp + OFF_IW2, cb, qd, ln, a4);
    epi16<1>(a4, ib2, cb, qd, ln, &X[0][0], 264);
    __syncthreads();

    // zinv = y2 @ M3 + c3 -> Y (y1 dead)
    gemm16<128, 128>(&X[0][0], 264, wp + OFF_M3, cb, qd, ln, a4);
    {
        int col = cb + ln;
        float bb = c3f[col];
#pragma unroll
        for (int rt = 0; rt < 2; ++rt)
#pragma unroll
            for (int r = 0; r < 4; ++r)
                Y[rt * 16 + qd * 4 + r][col] = (f16_t)(a4[rt][r] + bb);
    }
    __syncthreads();

    // coalesced store: per node 512B contiguous = [z | zinv]
#pragma unroll
    for (int i = 0; i < 2; ++i) {
        int q = i * 512 + tid;
        int node = q >> 5;
        int seg = q & 31;
        int row = row0 + node;
        if (row < M) {
            f16x8 v = (seg < 16) ? *(const f16x8*)&X[node][128 + seg * 8]
                                 : *(const f16x8*)&Y[node][(seg - 16) * 8];
            *(f16x8*)&zbuf[(size_t)row * 256 + seg * 8] = v;
        }
    }
}

// ---------------------------------------------------------------------------
// kernelB: 512 thr / 32 rows. Phase 0 = mean gather (half-wave per node,
// 2 passes). Buffer ping-pong A/B2/C, 8 barriers.
// ---------------------------------------------------------------------------
__global__ __launch_bounds__(512, 8) void kernelB(
    const f16_t* __restrict__ zbuf, const int* __restrict__ ridx,
    const int* __restrict__ offs, const int* __restrict__ cnt,
    const float* __restrict__ ab1, const int* __restrict__ invf,
    float* __restrict__ out, const f16_t* __restrict__ wp,
    const float* __restrict__ ab2, const float* __restrict__ ab3,
    const float* __restrict__ ib1, const float* __restrict__ ib2,
    const float* __restrict__ ib3, const float* __restrict__ pb1,
    const float* __restrict__ pb2, int M)
{
    __shared__ f16_t C[32][264];
    __shared__ f16_t A[32][136];
    __shared__ f16_t B2[32][136];
    __shared__ int sflag[32];

    const int tid = threadIdx.x;
    const int row0 = blockIdx.x * 32;
    const int lane = tid & 63;
    const int wv = tid >> 6;
    const int qd = lane >> 4;
    const int ln = lane & 15;
    const int cb2 = wv * 16;
    const int l31 = lane & 31;
    const int kh = lane >> 5;
    const int cb32 = wv * 32;

    // ---- phase 0: mean gather, half-wave (32 lanes x f16x4 = 256B row) per node
    const int hw = tid >> 5;          // half-wave 0..15
    const int hl = tid & 31;          // lane in half
    const int hbase = lane & 32;      // shfl base within wave
    const f16x4* zp4 = (const f16x4*)zbuf;   // row = 32 f16x4

#pragma unroll
    for (int pass = 0; pass < 2; ++pass) {
        int nl = pass * 16 + hw;
        int row = row0 + nl;
        float s0 = 0.f, s1 = 0.f, s2 = 0.f, s3 = 0.f;
        int c = 0;
        if (row < M) {
            int beg = offs[row];
            c = cnt[row];
            for (int base = 0; base < c; base += 32) {
                int rem = c - base; if (rem > 32) rem = 32;
                int myr = (hl < rem) ? ridx[beg + base + hl] : 0;
                int j = 0;
                for (; j + 16 <= rem; j += 16) {
                    f16x4 v[16];
#pragma unroll
                    for (int i = 0; i < 16; ++i) {
                        int rr = __shfl(myr, hbase + j + i);
                        v[i] = zp4[(size_t)rr * 32 + hl];
                    }
#pragma unroll
                    for (int i = 0; i < 16; ++i)
                        acc_f16x4(s0, s1, s2, s3, v[i]);
                }
                for (; j + 8 <= rem; j += 8) {
                    f16x4 v[8];
#pragma unroll
                    for (int i = 0; i < 8; ++i) {
                        int rr = __shfl(myr, hbase + j + i);
                        v[i] = zp4[(size_t)rr * 32 + hl];
                    }
#pragma unroll
                    for (int i = 0; i < 8; ++i)
                        acc_f16x4(s0, s1, s2, s3, v[i]);
                }
                for (; j < rem; ++j) {
                    int rr = __shfl(myr, hbase + j);
                    f16x4 vv = zp4[(size_t)rr * 32 + hl];
                    acc_f16x4(s0, s1, s2, s3, vv);
                }
            }
        }
        float invc = 1.0f / fmaxf((float)c, 1.0f);
        float4 bv = *(const float4*)&ab1[hl * 4];
        float m0 = leaky01(s0 * invc + bv.x);
        float m1 = leaky01(s1 * invc + bv.y);
        float m2 = leaky01(s2 * invc + bv.z);
        float m3 = leaky01(s3 * invc + bv.w);
        *(f16x4*)&A[nl][hl * 4] = (f16x4){(f16_t)m0, (f16_t)m1, (f16_t)m2, (f16_t)m3};
    }
    if (tid < 32) {
        int rr = row0 + tid;
        sflag[tid] = (rr < M) ? invf[rr] : 0;
    }
    __syncthreads();                                   // S1: A, sflag ready

    f32x4 a4[2];
    f32x16 c32;

    // L2a: u = leaky(y@aW2 + ab2): A -> B2
    gemm16<128, 128>(&A[0][0], 136, wp + OFF_AW2, cb2, qd, ln, a4);
    epi16<1>(a4, ab2, cb2, qd, ln, &B2[0][0], 136);
    __syncthreads();                                   // S2: B2 ready

    // L3a: res = u@aW3 + ab3: B2 -> C
    gemm32<128, 256>(&B2[0][0], 136, wp + OFF_AW3, cb32, l31, kh, c32);
    epi32<0>(c32, ab3, cb32, l31, kh, &C[0][0], 264);
    __syncthreads();                                   // S3: C ready

    // inv layer1: t1 = leaky(res@iW1 + ib1): C -> A  (A dead since S2)
    gemm16<256, 128>(&C[0][0], 264, wp + OFF_IW1, cb2, qd, ln, a4);
    epi16<1>(a4, ib1, cb2, qd, ln, &A[0][0], 136);
    __syncthreads();                                   // S4: A ready

    // inv layer2: t2 = leaky(t1@iW2 + ib2): A -> B2  (B2 dead since S3)
    gemm16<128, 128>(&A[0][0], 136, wp + OFF_IW2, cb2, qd, ln, a4);
    epi16<1>(a4, ib2, cb2, qd, ln, &B2[0][0], 136);
    __syncthreads();                                   // S5: B2 ready

    // inv layer3: overwrite C rows where flag set: B2 -> C-masked
    gemm32<128, 256>(&B2[0][0], 136, wp + OFF_IW3, cb32, l31, kh, c32);
    {
        int col = cb32 + l31;
        float bb = ib3[col];
#pragma unroll
        for (int r = 0; r < 16; ++r) {
            int lrow = (r & 3) + 8 * (r >> 2) + 4 * kh;
            if (sflag[lrow] == 1) C[lrow][col] = (f16_t)(c32[r] + bb);
        }
    }
    __syncthreads();                                   // S6: C (selected) ready

    // proj1: p1 = relu(sel@pW1 + pb1): C -> C (in place)
    gemm32<256, 256>(&C[0][0], 264, wp + OFF_PW1, cb32, l31, kh, c32);
    __syncthreads();                                   // S7: all reads of C done
    epi32<2>(c32, pb1, cb32, l31, kh, &C[0][0], 264);
    __syncthreads();                                   // S8: C ready

    // proj2 -> out
    gemm32<256, 256>(&C[0][0], 264, wp + OFF_PW2, cb32, l31, kh, c32);
    {
        int col = cb32 + l31;
        float bb = pb2[col];
#pragma unroll
        for (int r = 0; r < 16; ++r) {
            int lrow = (r & 3) + 8 * (r >> 2) + 4 * kh;
            int row = row0 + lrow;
            if (row < M) out[(size_t)row * 256 + col] = c32[r] + bb;
        }
    }
}

extern "C" void kernel_launch(void* const* d_in, const int* in_sizes, int n_in,
                              void* d_out, int out_size, void* d_ws, size_t ws_size,
                              hipStream_t stream)
{
    const float* h   = (const float*)d_in[0];
    const int* src   = (const int*)d_in[1];
    const int* dst   = (const int*)d_in[2];
    const int* r     = (const int*)d_in[3];
    const int* inv   = (const int*)d_in[4];
    const float* iW1 = (const float*)d_in[5];
    const float* ib1 = (const float*)d_in[6];
    const float* iW2 = (const float*)d_in[7];
    const float* ib2 = (const float*)d_in[8];
    const float* iW3 = (const float*)d_in[9];
    const float* ib3 = (const float*)d_in[10];
    const float* aW1 = (const float*)d_in[11];
    const float* ab1 = (const float*)d_in[12];
    const float* aW2 = (const float*)d_in[13];
    const float* ab2 = (const float*)d_in[14];
    const float* aW3 = (const float*)d_in[15];
    const float* ab3 = (const float*)d_in[16];
    const float* pW1 = (const float*)d_in[17];
    const float* pb1 = (const float*)d_in[18];
    const float* pW2 = (const float*)d_in[19];
    const float* pb2 = (const float*)d_in[20];

    const int N = in_sizes[0] / 256;
    const int E = in_sizes[1];
    float* out = (float*)d_out;

    // workspace carve-up
    f16_t* zbuf = (f16_t*)d_ws;                        // 2N*128 f16 (z|zinv per node)
    int* cnt    = (int*)(zbuf + (size_t)2 * N * 128);  // N
    int* offs   = cnt + N;                             // N
    int* cursor = offs + N;                            // N
    int* bsum   = cursor + N;                          // 256
    int* ridx   = bsum + 256;                          // E
    f16_t* wp   = (f16_t*)(ridx + E);                  // WP_TOTAL packed f16
    float* c3f  = (float*)(wp + WP_TOTAL);             // 128

    (void)hipMemsetAsync(cnt, 0, (size_t)N * sizeof(int), stream);

    const int tiles = (N + 31) / 32;
    const int EB = (E + 511) / 512;
    const int NB = (N + 255) / 256;

    // 1) pack + M3/c3 + edge count (one launch; independent block ranges)
    prep_kernel<<<1057 + EB, 512, 0, stream>>>(iW1, iW2, iW3, aW1, aW2, aW3,
                                               pW1, pW2, ib3, wp, c3f,
                                               dst, cnt, E);

    // 2) CSR scan (multi-block, proven fast)
    scan1<<<NB, 256, 0, stream>>>(cnt, offs, bsum, N);
    if (NB <= 256) {
        scan3b<<<NB, 256, 0, stream>>>(offs, bsum, cursor, N, NB);
    } else {
        scan2<<<1, 1, 0, stream>>>(bsum, NB);
        scan3<<<NB, 256, 0, stream>>>(offs, bsum, cursor, N);
    }

    // 3) kernelA blocks + CSR fill blocks, concurrent
    fillA<<<tiles + EB, 512, 0, stream>>>(h, zbuf, wp, ib1, ib2, c3f, N,
                                          tiles, dst, src, r, cursor, ridx, E);

    // 4) fused: mean gather + L2a,L3a + cond inv-MLP + proj1,proj2
    kernelB<<<tiles, 512, 0, stream>>>(zbuf, ridx, offs, cnt, ab1, inv, out, wp,
                                       ab2, ab3, ib1, ib2, ib3, pb1, pb2, N);
}

// Round 9
// 322.825 us; speedup vs baseline: 1.3393x; 1.0004x over previous
//
#include <hip/hip_runtime.h>

typedef _Float16 f16_t;
typedef f16_t f16x2 __attribute__((ext_vector_type(2)));
typedef f16_t f16x4 __attribute__((ext_vector_type(4)));
typedef f16_t f16x8 __attribute__((ext_vector_type(8)));
typedef float f32x4 __attribute__((ext_vector_type(4)));
typedef float f32x16 __attribute__((ext_vector_type(16)));

#define MFMA16H(a, b, c) __builtin_amdgcn_mfma_f32_16x16x32_f16(a, b, c, 0, 0, 0)
#define MFMA32H(a, b, c) __builtin_amdgcn_mfma_f32_32x32x16_f16(a, b, c, 0, 0, 0)

__device__ __forceinline__ float leaky01(float v) { return v >= 0.f ? v : 0.01f * v; }

// accumulate one f16x4 row fragment into 4 f32 sums via v_dot2_f32_f16
__device__ __forceinline__ void acc_f16x4(float& s0, float& s1, float& s2, float& s3,
                                          f16x4 v)
{
#if __has_builtin(__builtin_amdgcn_fdot2)
    const f16x2 K10 = (f16x2){(f16_t)1.0f, (f16_t)0.0f};
    const f16x2 K01 = (f16x2){(f16_t)0.0f, (f16_t)1.0f};
    f16x2 lo = (f16x2){v.x, v.y};
    f16x2 hi = (f16x2){v.z, v.w};
    s0 = __builtin_amdgcn_fdot2(lo, K10, s0, false);
    s1 = __builtin_amdgcn_fdot2(lo, K01, s1, false);
    s2 = __builtin_amdgcn_fdot2(hi, K10, s2, false);
    s3 = __builtin_amdgcn_fdot2(hi, K01, s3, false);
#else
    s0 += (float)v.x; s1 += (float)v.y; s2 += (float)v.z; s3 += (float)v.w;
#endif
}

// packed-weight offsets (f16 elements)
#define OFF_IW1 0         // 256x128
#define OFF_IW2 32768     // 128x128
#define OFF_IW3 49152     // 128x256
#define OFF_AW1 81920     // 256x128
#define OFF_AW2 114688    // 128x128
#define OFF_AW3 131072    // 128x256
#define OFF_PW1 163840    // 256x256
#define OFF_PW2 229376    // 256x256
#define OFF_M3  294912    // 128x128
#define WP_TOTAL 311296

// ---------------------------------------------------------------------------
// Narrow (128-col) GEMM, 32 rows: 8 waves x 16 cols, 2 row-tiles of 16.
// ---------------------------------------------------------------------------
template<int KD, int NC>
__device__ __forceinline__ void gemm16(
    const f16_t* __restrict__ a, int sa, const f16_t* __restrict__ B,
    int cb, int qd, int ln, f32x4 (&acc)[2])
{
    acc[0] = (f32x4){0.f, 0.f, 0.f, 0.f};
    acc[1] = acc[0];
#pragma unroll
    for (int k0 = 0; k0 < KD; k0 += 32) {
        int ka = k0 + qd * 8;
        f16x8 b = *(const f16x8*)(B + ((size_t)((k0 >> 5) * 4 + qd) * NC + cb + ln) * 8);
        f16x8 a0 = *(const f16x8*)&a[ln * sa + ka];
        f16x8 a1 = *(const f16x8*)&a[(16 + ln) * sa + ka];
        acc[0] = MFMA16H(a0, b, acc[0]);
        acc[1] = MFMA16H(a1, b, acc[1]);
    }
}

// ---------------------------------------------------------------------------
// Wide GEMM, 32 rows: per wave 32 cols x one 32-row subtile.
// ---------------------------------------------------------------------------
template<int KD, int NC>
__device__ __forceinline__ void gemm32(
    const f16_t* __restrict__ a, int sa, const f16_t* __restrict__ B,
    int cb, int l31, int kh, f32x16 &o)
{
    f32x16 c;
#pragma unroll
    for (int i = 0; i < 16; ++i) c[i] = 0.f;
    const int ar = l31 * sa + kh * 8;
    const int bcol = cb + l31;
#pragma unroll
    for (int kc = 0; kc < KD; kc += 32) {
        f16x8 b0 = *(const f16x8*)(B + ((size_t)((kc >> 3) + kh) * NC + bcol) * 8);
        f16x8 b1 = *(const f16x8*)(B + ((size_t)((kc >> 3) + 2 + kh) * NC + bcol) * 8);
        f16x8 a0 = *(const f16x8*)&a[ar + kc];
        f16x8 a1 = *(const f16x8*)&a[ar + kc + 16];
        c = MFMA32H(a0, b0, c);
        c = MFMA32H(a1, b1, c);
    }
    o = c;
}

// narrow epilogue -> f16 LDS. act: 0 none, 1 leaky, 2 relu
template<int ACT>
__device__ __forceinline__ void epi16(
    f32x4 (&acc)[2], const float* __restrict__ bias,
    int cb, int qd, int ln, f16_t* d, int stride)
{
    int col = cb + ln;
    float bb = bias[col];
#pragma unroll
    for (int rt = 0; rt < 2; ++rt)
#pragma unroll
        for (int r = 0; r < 4; ++r) {
            float v = acc[rt][r] + bb;
            if (ACT == 1) v = leaky01(v);
            else if (ACT == 2) v = fmaxf(v, 0.f);
            d[(rt * 16 + qd * 4 + r) * stride + col] = (f16_t)v;
        }
}

// wide epilogue -> f16 LDS. C/D layout: col=lane&31, row=(r&3)+8*(r>>2)+4*kh.
template<int ACT>
__device__ __forceinline__ void epi32(
    const f32x16 &a0, const float* __restrict__ bias,
    int cb, int l31, int kh, f16_t* d, int stride)
{
    int col = cb + l31;
    float bb = bias[col];
#pragma unroll
    for (int r = 0; r < 16; ++r) {
        float v = a0[r] + bb;
        if (ACT == 1) v = leaky01(v);
        else if (ACT == 2) v = fmaxf(v, 0.f);
        int row = (r & 3) + 8 * (r >> 2) + 4 * kh;
        d[row * stride + col] = (f16_t)v;
    }
}

// ---------------------------------------------------------------------------
// prep_kernel: ONE launch for {weight pack, M3 = iW3@aW1, c3 = ib3@aW1,
// CSR edge count} — all mutually independent block ranges.
// ---------------------------------------------------------------------------
__global__ __launch_bounds__(512) void prep_kernel(
    const float* s0, const float* s1, const float* s2, const float* s3,
    const float* s4, const float* s5, const float* s6, const float* s7,
    const float* __restrict__ ib3, f16_t* dst, float* __restrict__ c3f,
    const int* __restrict__ dstE, int* __restrict__ cnt, int E)
{
    const int tid = threadIdx.x;
    const int bid = blockIdx.x;

    if (bid < 1024) {                     // weight pack
        const float* srcs[8] = {s0, s1, s2, s3, s4, s5, s6, s7};
        const int lgN[8] = {7, 7, 8, 7, 7, 8, 8, 8};
        const int sz[8]  = {32768, 16384, 32768, 32768, 16384, 32768, 65536, 65536};
        const int off[8] = {OFF_IW1, OFF_IW2, OFF_IW3, OFF_AW1, OFF_AW2, OFF_AW3,
                            OFF_PW1, OFF_PW2};
        int m = bid >> 7;
        int idx = (bid & 127) * 512 + tid;
        if (idx >= sz[m]) return;
        int lg = lgN[m];
        int Nc = 1 << lg;
        int k = idx >> lg;
        int n = idx & (Nc - 1);
        int p = ((k >> 3) * Nc + n) * 8 + (k & 7);
        dst[off[m] + p] = (f16_t)srcs[m][idx];
    } else if (bid < 1056) {              // M3 = iW3 @ aW1
        int idx = (bid - 1024) * 512 + tid;    // < 16384
        int k = idx >> 7, j = idx & 127;
        float s = 0.f;
        for (int t = 0; t < 256; ++t) s += s2[k * 256 + t] * s3[t * 128 + j];
        int p = ((k >> 3) * 128 + j) * 8 + (k & 7);
        dst[OFF_M3 + p] = (f16_t)s;
    } else if (bid == 1056) {             // c3 = ib3 @ aW1
        int j = tid;
        if (j < 128) {
            float s = 0.f;
            for (int t = 0; t < 256; ++t) s += ib3[t] * s3[t * 128 + j];
            c3f[j] = s;
        }
    } else {                              // CSR edge count
        int e = (bid - 1057) * 512 + tid;
        if (e < E) atomicAdd(&cnt[dstE[e]], 1);
    }
}

// ---------------------------------------------------------------------------
// CSR scan: multi-block (proven fast path). scan1 -> scan3b (merged scan2).
// ---------------------------------------------------------------------------
__global__ void scan1(const int* __restrict__ cnt, int* __restrict__ offs,
                      int* __restrict__ bsum, int Nn)
{
    __shared__ int s[256];
    int tid = threadIdx.x;
    int g = blockIdx.x * 256 + tid;
    int v = (g < Nn) ? cnt[g] : 0;
    s[tid] = v;
    __syncthreads();
    for (int off = 1; off < 256; off <<= 1) {
        int u = (tid >= off) ? s[tid - off] : 0;
        __syncthreads();
        s[tid] += u;
        __syncthreads();
    }
    if (g < Nn) offs[g] = s[tid] - v;          // block-exclusive
    if (tid == 255) bsum[blockIdx.x] = s[255];
}

// requires NB <= 256 (true at N=50k: NB=196)
__global__ void scan3b(int* __restrict__ offs, const int* __restrict__ bsum,
                       int* __restrict__ cursor, int Nn, int NB)
{
    __shared__ int s[256];
    int tid = threadIdx.x;
    int bid = blockIdx.x;
    int v = (tid < NB) ? bsum[tid] : 0;
    s[tid] = v;
    __syncthreads();
    for (int off = 1; off < 256; off <<= 1) {
        int u = (tid >= off) ? s[tid - off] : 0;
        __syncthreads();
        s[tid] += u;
        __syncthreads();
    }
    int base = (bid > 0) ? s[bid - 1] : 0;     // sum of bsum[0..bid-1]
    int g = bid * 256 + tid;
    if (g < Nn) {
        int o = offs[g] + base;
        offs[g] = o;
        cursor[g] = o;
    }
}

// fallback path kernels (NB > 256; unused at N=50k)
__global__ void scan2(int* __restrict__ bsum, int NB)
{
    if (threadIdx.x == 0) {
        int run = 0;
        for (int i = 0; i < NB; ++i) { int v = bsum[i]; bsum[i] = run; run += v; }
    }
}

__global__ void scan3(int* __restrict__ offs, const int* __restrict__ bsum,
                      int* __restrict__ cursor, int Nn)
{
    int g = blockIdx.x * 256 + threadIdx.x;
    if (g < Nn) {
        int o = offs[g] + bsum[blockIdx.x];
        offs[g] = o;
        cursor[g] = o;
    }
}

// ---------------------------------------------------------------------------
// fillA: kernelA blocks (bid < tiles) concurrent with CSR fill blocks.
// __launch_bounds__(512, 4): VGPR cap 128 so the compiler can keep staging
// loads / GEMM fragments in flight (the (512,8) cap forced VGPR=32 and
// serialized all memory ops — R8 counters: all pipes <17% busy).
// ---------------------------------------------------------------------------
__global__ __launch_bounds__(512, 4) void fillA(
    const float* __restrict__ h, f16_t* __restrict__ zbuf,
    const f16_t* __restrict__ wp, const float* __restrict__ ib1,
    const float* __restrict__ ib2, const float* __restrict__ c3f, int M,
    int tiles, const int* __restrict__ dstE, const int* __restrict__ srcE,
    const int* __restrict__ rE, int* __restrict__ cursor,
    int* __restrict__ ridx, int E)
{
    __shared__ f16_t X[32][264];
    __shared__ f16_t Y[32][136];

    const int tid = threadIdx.x;

    if ((int)blockIdx.x >= tiles) {       // CSR fill blocks
        int e = (blockIdx.x - tiles) * 512 + tid;
        if (e < E) {
            int p = atomicAdd(&cursor[dstE[e]], 1);
            ridx[p] = srcE[e] * 2 + rE[e];
        }
        return;
    }

    const int row0 = blockIdx.x * 32;
    const int lane = tid & 63;
    const int wv = tid >> 6;          // 0..7
    const int qd = lane >> 4;
    const int ln = lane & 15;
    const int cb = wv * 16;
    const int l31 = lane & 31;
    const int kh = lane >> 5;

    // stage h (32 x 256 fp32) -> f16
    {
        const float4* src4 = (const float4*)(h + (size_t)row0 * 256);
#pragma unroll
        for (int i = 0; i < 4; ++i) {
            int q = i * 512 + tid;
            int row = q >> 6;
            int kc = (q & 63) * 4;
            float4 v = make_float4(0.f, 0.f, 0.f, 0.f);
            if (row0 + row < M) v = src4[q];
            *(f16x4*)&X[row][kc] = (f16x4){(f16_t)v.x, (f16_t)v.y, (f16_t)v.z, (f16_t)v.w};
        }
    }
    __syncthreads();

    // dual wide: waves 0-3 -> z (aW1), waves 4-7 -> y1 (iW1); 32 cols/wave
    {
        const bool isz = wv < 4;
        const int cb32 = (wv & 3) * 32;
        const f16_t* Bw = wp + (isz ? OFF_AW1 : OFF_IW1);
        f32x16 z;
        gemm32<256, 128>(&X[0][0], 264, Bw, cb32, l31, kh, z);
        __syncthreads();   // all waves done reading h
        int col = cb32 + l31;
        if (isz) {
            // z -> X[:, 128+col] (staged for the coalesced store)
#pragma unroll
            for (int r = 0; r < 16; ++r) {
                int lrow = (r & 3) + 8 * (r >> 2) + 4 * kh;
                X[lrow][128 + col] = (f16_t)z[r];
            }
        } else {
            float bb = ib1[col];
#pragma unroll
            for (int r = 0; r < 16; ++r) {
                int lrow = (r & 3) + 8 * (r >> 2) + 4 * kh;
                Y[lrow][col] = (f16_t)leaky01(z[r] + bb);
            }
        }
    }
    __syncthreads();

    f32x4 a4[2];

    // y2 = leaky(y1@iW2 + ib2) -> X cols 0..127 (h dead; z at 128..255)
    gemm16<128, 128>(&Y[0][0], 136, wp + OFF_IW2, cb, qd, ln, a4);
    epi16<1>(a4, ib2, cb, qd, ln, &X[0][0], 264);
    __syncthreads();

    // zinv = y2 @ M3 + c3 -> Y (y1 dead)
    gemm16<128, 128>(&X[0][0], 264, wp + OFF_M3, cb, qd, ln, a4);
    {
        int col = cb + ln;
        float bb = c3f[col];
#pragma unroll
        for (int rt = 0; rt < 2; ++rt)
#pragma unroll
            for (int r = 0; r < 4; ++r)
                Y[rt * 16 + qd * 4 + r][col] = (f16_t)(a4[rt][r] + bb);
    }
    __syncthreads();

    // coalesced store: per node 512B contiguous = [z | zinv]
#pragma unroll
    for (int i = 0; i < 2; ++i) {
        int q = i * 512 + tid;
        int node = q >> 5;
        int seg = q & 31;
        int row = row0 + node;
        if (row < M) {
            f16x8 v = (seg < 16) ? *(const f16x8*)&X[node][128 + seg * 8]
                                 : *(const f16x8*)&Y[node][(seg - 16) * 8];
            *(f16x8*)&zbuf[(size_t)row * 256 + seg * 8] = v;
        }
    }
}

// ---------------------------------------------------------------------------
// kernelB: 512 thr / 32 rows. Phase 0 = mean gather (half-wave per node,
// 2 passes, 16-deep load batches). __launch_bounds__(512, 4): VGPR cap 128
// so the v[16] batch (32 VGPRs of results) can actually stay in flight.
// ---------------------------------------------------------------------------
__global__ __launch_bounds__(512, 4) void kernelB(
    const f16_t* __restrict__ zbuf, const int* __restrict__ ridx,
    const int* __restrict__ offs, const int* __restrict__ cnt,
    const float* __restrict__ ab1, const int* __restrict__ invf,
    float* __restrict__ out, const f16_t* __restrict__ wp,
    const float* __restrict__ ab2, const float* __restrict__ ab3,
    const float* __restrict__ ib1, const float* __restrict__ ib2,
    const float* __restrict__ ib3, const float* __restrict__ pb1,
    const float* __restrict__ pb2, int M)
{
    __shared__ f16_t C[32][264];
    __shared__ f16_t A[32][136];
    __shared__ f16_t B2[32][136];
    __shared__ int sflag[32];

    const int tid = threadIdx.x;
    const int row0 = blockIdx.x * 32;
    const int lane = tid & 63;
    const int wv = tid >> 6;
    const int qd = lane >> 4;
    const int ln = lane & 15;
    const int cb2 = wv * 16;
    const int l31 = lane & 31;
    const int kh = lane >> 5;
    const int cb32 = wv * 32;

    // ---- phase 0: mean gather, half-wave (32 lanes x f16x4 = 256B row) per node
    const int hw = tid >> 5;          // half-wave 0..15
    const int hl = tid & 31;          // lane in half
    const int hbase = lane & 32;      // shfl base within wave
    const f16x4* zp4 = (const f16x4*)zbuf;   // row = 32 f16x4

#pragma unroll
    for (int pass = 0; pass < 2; ++pass) {
        int nl = pass * 16 + hw;
        int row = row0 + nl;
        float s0 = 0.f, s1 = 0.f, s2 = 0.f, s3 = 0.f;
        int c = 0;
        if (row < M) {
            int beg = offs[row];
            c = cnt[row];
            for (int base = 0; base < c; base += 32) {
                int rem = c - base; if (rem > 32) rem = 32;
                int myr = (hl < rem) ? ridx[beg + base + hl] : 0;
                int j = 0;
                for (; j + 16 <= rem; j += 16) {
                    f16x4 v[16];
#pragma unroll
                    for (int i = 0; i < 16; ++i) {
                        int rr = __shfl(myr, hbase + j + i);
                        v[i] = zp4[(size_t)rr * 32 + hl];
                    }
#pragma unroll
                    for (int i = 0; i < 16; ++i)
                        acc_f16x4(s0, s1, s2, s3, v[i]);
                }
                for (; j + 8 <= rem; j += 8) {
                    f16x4 v[8];
#pragma unroll
                    for (int i = 0; i < 8; ++i) {
                        int rr = __shfl(myr, hbase + j + i);
                        v[i] = zp4[(size_t)rr * 32 + hl];
                    }
#pragma unroll
                    for (int i = 0; i < 8; ++i)
                        acc_f16x4(s0, s1, s2, s3, v[i]);
                }
                for (; j < rem; ++j) {
                    int rr = __shfl(myr, hbase + j);
                    f16x4 vv = zp4[(size_t)rr * 32 + hl];
                    acc_f16x4(s0, s1, s2, s3, vv);
                }
            }
        }
        float invc = 1.0f / fmaxf((float)c, 1.0f);
        float4 bv = *(const float4*)&ab1[hl * 4];
        float m0 = leaky01(s0 * invc + bv.x);
        float m1 = leaky01(s1 * invc + bv.y);
        float m2 = leaky01(s2 * invc + bv.z);
        float m3 = leaky01(s3 * invc + bv.w);
        *(f16x4*)&A[nl][hl * 4] = (f16x4){(f16_t)m0, (f16_t)m1, (f16_t)m2, (f16_t)m3};
    }
    if (tid < 32) {
        int rr = row0 + tid;
        sflag[tid] = (rr < M) ? invf[rr] : 0;
    }
    __syncthreads();                                   // S1: A, sflag ready

    f32x4 a4[2];
    f32x16 c32;

    // L2a: u = leaky(y@aW2 + ab2): A -> B2
    gemm16<128, 128>(&A[0][0], 136, wp + OFF_AW2, cb2, qd, ln, a4);
    epi16<1>(a4, ab2, cb2, qd, ln, &B2[0][0], 136);
    __syncthreads();                                   // S2: B2 ready

    // L3a: res = u@aW3 + ab3: B2 -> C
    gemm32<128, 256>(&B2[0][0], 136, wp + OFF_AW3, cb32, l31, kh, c32);
    epi32<0>(c32, ab3, cb32, l31, kh, &C[0][0], 264);
    __syncthreads();                                   // S3: C ready

    // inv layer1: t1 = leaky(res@iW1 + ib1): C -> A  (A dead since S2)
    gemm16<256, 128>(&C[0][0], 264, wp + OFF_IW1, cb2, qd, ln, a4);
    epi16<1>(a4, ib1, cb2, qd, ln, &A[0][0], 136);
    __syncthreads();                                   // S4: A ready

    // inv layer2: t2 = leaky(t1@iW2 + ib2): A -> B2  (B2 dead since S3)
    gemm16<128, 128>(&A[0][0], 136, wp + OFF_IW2, cb2, qd, ln, a4);
    epi16<1>(a4, ib2, cb2, qd, ln, &B2[0][0], 136);
    __syncthreads();                                   // S5: B2 ready

    // inv layer3: overwrite C rows where flag set: B2 -> C-masked
    gemm32<128, 256>(&B2[0][0], 136, wp + OFF_IW3, cb32, l31, kh, c32);
    {
        int col = cb32 + l31;
        float bb = ib3[col];
#pragma unroll
        for (int r = 0; r < 16; ++r) {
            int lrow = (r & 3) + 8 * (r >> 2) + 4 * kh;
            if (sflag[lrow] == 1) C[lrow][col] = (f16_t)(c32[r] + bb);
        }
    }
    __syncthreads();                                   // S6: C (selected) ready

    // proj1: p1 = relu(sel@pW1 + pb1): C -> C (in place)
    gemm32<256, 256>(&C[0][0], 264, wp + OFF_PW1, cb32, l31, kh, c32);
    __syncthreads();                                   // S7: all reads of C done
    epi32<2>(c32, pb1, cb32, l31, kh, &C[0][0], 264);
    __syncthreads();                                   // S8: C ready

    // proj2 -> out
    gemm32<256, 256>(&C[0][0], 264, wp + OFF_PW2, cb32, l31, kh, c32);
    {
        int col = cb32 + l31;
        float bb = pb2[col];
#pragma unroll
        for (int r = 0; r < 16; ++r) {
            int lrow = (r & 3) + 8 * (r >> 2) + 4 * kh;
            int row = row0 + lrow;
            if (row < M) out[(size_t)row * 256 + col] = c32[r] + bb;
        }
    }
}

extern "C" void kernel_launch(void* const* d_in, const int* in_sizes, int n_in,
                              void* d_out, int out_size, void* d_ws, size_t ws_size,
                              hipStream_t stream)
{
    const float* h   = (const float*)d_in[0];
    const int* src   = (const int*)d_in[1];
    const int* dst   = (const int*)d_in[2];
    const int* r     = (const int*)d_in[3];
    const int* inv   = (const int*)d_in[4];
    const float* iW1 = (const float*)d_in[5];
    const float* ib1 = (const float*)d_in[6];
    const float* iW2 = (const float*)d_in[7];
    const float* ib2 = (const float*)d_in[8];
    const float* iW3 = (const float*)d_in[9];
    const float* ib3 = (const float*)d_in[10];
    const float* aW1 = (const float*)d_in[11];
    const float* ab1 = (const float*)d_in[12];
    const float* aW2 = (const float*)d_in[13];
    const float* ab2 = (const float*)d_in[14];
    const float* aW3 = (const float*)d_in[15];
    const float* ab3 = (const float*)d_in[16];
    const float* pW1 = (const float*)d_in[17];
    const float* pb1 = (const float*)d_in[18];
    const float* pW2 = (const float*)d_in[19];
    const float* pb2 = (const float*)d_in[20];

    const int N = in_sizes[0] / 256;
    const int E = in_sizes[1];
    float* out = (float*)d_out;

    // workspace carve-up
    f16_t* zbuf = (f16_t*)d_ws;                        // 2N*128 f16 (z|zinv per node)
    int* cnt    = (int*)(zbuf + (size_t)2 * N * 128);  // N
    int* offs   = cnt + N;                             // N
    int* cursor = offs + N;                            // N
    int* bsum   = cursor + N;                          // 256
    int* ridx   = bsum + 256;                          // E
    f16_t* wp   = (f16_t*)(ridx + E);                  // WP_TOTAL packed f16
    float* c3f  = (float*)(wp + WP_TOTAL);             // 128

    (void)hipMemsetAsync(cnt, 0, (size_t)N * sizeof(int), stream);

    const int tiles = (N + 31) / 32;
    const int EB = (E + 511) / 512;
    const int NB = (N + 255) / 256;

    // 1) pack + M3/c3 + edge count (one launch; independent block ranges)
    prep_kernel<<<1057 + EB, 512, 0, stream>>>(iW1, iW2, iW3, aW1, aW2, aW3,
                                               pW1, pW2, ib3, wp, c3f,
                                               dst, cnt, E);

    // 2) CSR scan (multi-block, proven fast)
    scan1<<<NB, 256, 0, stream>>>(cnt, offs, bsum, N);
    if (NB <= 256) {
        scan3b<<<NB, 256, 0, stream>>>(offs, bsum, cursor, N, NB);
    } else {
        scan2<<<1, 1, 0, stream>>>(bsum, NB);
        scan3<<<NB, 256, 0, stream>>>(offs, bsum, cursor, N);
    }

    // 3) kernelA blocks + CSR fill blocks, concurrent
    fillA<<<tiles + EB, 512, 0, stream>>>(h, zbuf, wp, ib1, ib2, c3f, N,
                                          tiles, dst, src, r, cursor, ridx, E);

    // 4) fused: mean gather + L2a,L3a + cond inv-MLP + proj1,proj2
    kernelB<<<tiles, 512, 0, stream>>>(zbuf, ridx, offs, cnt, ab1, inv, out, wp,
                                       ab2, ab3, ib1, ib2, ib3, pb1, pb2, N);
}